// Round 1
// baseline (2000.790 us; speedup 1.0000x reference)
//
#include <hip/hip_runtime.h>
#include <stdint.h>

#define NN 100000
#define EE 800000
#define DD 128
#define HH 128
#define OO 64

typedef __attribute__((ext_vector_type(8))) short short8v;   // 8 x bf16 fragment
typedef __attribute__((ext_vector_type(4))) float f32x4;     // MFMA accumulator

__device__ __forceinline__ unsigned short f2bf(float f) {
    union { float f; unsigned int u; } v; v.f = f;
    unsigned int u = v.u;
    u = (u + 0x7fffu + ((u >> 16) & 1u)) >> 16;   // RNE
    return (unsigned short)u;
}
__device__ __forceinline__ float bf2f(unsigned short b) {
    union { unsigned int u; float f; } v; v.u = ((unsigned int)b) << 16;
    return v.f;
}

// ---------------- K1: p2a last-write-wins scatter ----------------
__global__ __launch_bounds__(256) void k_p2a(const int* __restrict__ pa_src,
                                             const int* __restrict__ pa_dst,
                                             unsigned long long* __restrict__ p2a) {
    int e = blockIdx.x * 256 + threadIdx.x;
    if (e >= EE) return;
    unsigned long long key = ((unsigned long long)(unsigned int)e << 32) | (unsigned int)pa_dst[e];
    atomicMax(&p2a[pa_src[e]], key);
}

// ---------------- K2: meta_dst = p2a[edge_ap.dst] ----------------
__global__ __launch_bounds__(256) void k_meta(const int* __restrict__ ap_dst,
                                              const unsigned long long* __restrict__ p2a,
                                              int* __restrict__ meta_dst) {
    int e = blockIdx.x * 256 + threadIdx.x;
    if (e >= EE) return;
    meta_dst[e] = (int)(p2a[ap_dst[e]] & 0xffffffffull);
}

// ---------------- K3: SAGE mean-aggregate (scatter) ----------------
// 32 threads per edge, 4 dims each (float4)
__global__ __launch_bounds__(256) void k_sageagg(const int* __restrict__ pa_src,
                                                 const int* __restrict__ pa_dst,
                                                 const float* __restrict__ x_paper,
                                                 float* __restrict__ agg,
                                                 int* __restrict__ cnt) {
    long gid = (long)blockIdx.x * 256 + threadIdx.x;
    int e = (int)(gid >> 5);
    if (e >= EE) return;
    int sub = (int)(gid & 31);
    int s = pa_src[e], d = pa_dst[e];
    float4 v = *(const float4*)(x_paper + (long)s * DD + sub * 4);
    float* dst = agg + (long)d * DD + sub * 4;
    atomicAdd(dst + 0, v.x);
    atomicAdd(dst + 1, v.y);
    atomicAdd(dst + 2, v.z);
    atomicAdd(dst + 3, v.w);
    if (sub == 0) atomicAdd(cnt + d, 1);
}

// ---------------- helpers for MFMA A fragments ----------------
__device__ __forceinline__ short8v ld_frag_scaled(const float* __restrict__ p, float scale) {
    const float4* q = (const float4*)p;
    float4 a = q[0], b = q[1];
    short8v w;
    w[0] = (short)f2bf(a.x * scale); w[1] = (short)f2bf(a.y * scale);
    w[2] = (short)f2bf(a.z * scale); w[3] = (short)f2bf(a.w * scale);
    w[4] = (short)f2bf(b.x * scale); w[5] = (short)f2bf(b.y * scale);
    w[6] = (short)f2bf(b.z * scale); w[7] = (short)f2bf(b.w * scale);
    return w;
}

// ---------------- K4: h = lrelu(mean@Wl^T + x@Wr^T + b), store bf16 ----------------
// 4 waves/block, 32 rows/wave -> 128 rows/block
__global__ __launch_bounds__(256) void k_sagegemm(const float* __restrict__ agg,
                                                  const int* __restrict__ cnt,
                                                  const float* __restrict__ xa,
                                                  const float* __restrict__ Wl,
                                                  const float* __restrict__ Wr,
                                                  const float* __restrict__ sb,
                                                  unsigned short* __restrict__ h) {
    __shared__ unsigned short wlds[2][HH * DD];   // 64 KiB, bf16, XOR-swizzled
    int t = threadIdx.x;
    // stage Wl, Wr (f32 -> bf16), swizzle 16B chunks within 128B stripes
    #pragma unroll
    for (int it = 0; it < 8; ++it) {
        int cid = t + it * 256;          // 2048 chunks of 8 elems
        int o = cid >> 4, c = cid & 15;
        int boff = (o * 256 + c * 16) ^ ((o & 7) << 4);
        {
            const float4* p = (const float4*)(Wl + (long)o * DD + c * 8);
            float4 a = p[0], b = p[1];
            short8v w;
            w[0]=(short)f2bf(a.x); w[1]=(short)f2bf(a.y); w[2]=(short)f2bf(a.z); w[3]=(short)f2bf(a.w);
            w[4]=(short)f2bf(b.x); w[5]=(short)f2bf(b.y); w[6]=(short)f2bf(b.z); w[7]=(short)f2bf(b.w);
            *(short8v*)((char*)(&wlds[0][0]) + boff) = w;
        }
        {
            const float4* p = (const float4*)(Wr + (long)o * DD + c * 8);
            float4 a = p[0], b = p[1];
            short8v w;
            w[0]=(short)f2bf(a.x); w[1]=(short)f2bf(a.y); w[2]=(short)f2bf(a.z); w[3]=(short)f2bf(a.w);
            w[4]=(short)f2bf(b.x); w[5]=(short)f2bf(b.y); w[6]=(short)f2bf(b.z); w[7]=(short)f2bf(b.w);
            *(short8v*)((char*)(&wlds[1][0]) + boff) = w;
        }
    }
    __syncthreads();

    int wave = t >> 6, lane = t & 63;
    int rowbase = blockIdx.x * 128 + wave * 32;
    int lr = lane & 15;
    int kq = (lane >> 4) * 8;
    int r0 = rowbase + lr, r1 = r0 + 16;
    int cr0 = (r0 < NN) ? r0 : 0;
    int cr1 = (r1 < NN) ? r1 : 0;
    float rc0 = 1.0f / fmaxf((float)cnt[cr0], 1.0f);
    float rc1 = 1.0f / fmaxf((float)cnt[cr1], 1.0f);

    f32x4 acc[2][8];
    #pragma unroll
    for (int i = 0; i < 2; ++i)
        #pragma unroll
        for (int j = 0; j < 8; ++j) { f32x4 z = {0.f,0.f,0.f,0.f}; acc[i][j] = z; }

    #pragma unroll
    for (int k0 = 0; k0 < DD; k0 += 32) {
        int kk = k0 + kq;
        short8v am0 = ld_frag_scaled(agg + (long)cr0 * DD + kk, rc0);
        short8v am1 = ld_frag_scaled(agg + (long)cr1 * DD + kk, rc1);
        short8v ax0 = ld_frag_scaled(xa + (long)cr0 * DD + kk, 1.0f);
        short8v ax1 = ld_frag_scaled(xa + (long)cr1 * DD + kk, 1.0f);
        #pragma unroll
        for (int nb = 0; nb < 8; ++nb) {
            int o = nb * 16 + lr;
            int boff = (o * 256 + kk * 2) ^ ((o & 7) << 4);
            short8v bl = *(const short8v*)((const char*)(&wlds[0][0]) + boff);
            short8v br = *(const short8v*)((const char*)(&wlds[1][0]) + boff);
            acc[0][nb] = __builtin_amdgcn_mfma_f32_16x16x32_bf16(am0, bl, acc[0][nb], 0, 0, 0);
            acc[1][nb] = __builtin_amdgcn_mfma_f32_16x16x32_bf16(am1, bl, acc[1][nb], 0, 0, 0);
            acc[0][nb] = __builtin_amdgcn_mfma_f32_16x16x32_bf16(ax0, br, acc[0][nb], 0, 0, 0);
            acc[1][nb] = __builtin_amdgcn_mfma_f32_16x16x32_bf16(ax1, br, acc[1][nb], 0, 0, 0);
        }
    }
    // epilogue: bias + leaky_relu(0.01) -> bf16
    int q = lane >> 4;
    #pragma unroll
    for (int rh = 0; rh < 2; ++rh) {
        #pragma unroll
        for (int nb = 0; nb < 8; ++nb) {
            int col = nb * 16 + lr;
            float bias = sb[col];
            #pragma unroll
            for (int r = 0; r < 4; ++r) {
                int row = rowbase + rh * 16 + q * 4 + r;
                if (row < NN) {
                    float v = acc[rh][nb][r] + bias;
                    v = (v >= 0.f) ? v : 0.01f * v;
                    h[(long)row * HH + col] = f2bf(v);
                }
            }
        }
    }
}

// ---------------- K5: hg = h @ gatW^T, store bf16 ----------------
__global__ __launch_bounds__(256) void k_gatgemm(const unsigned short* __restrict__ h,
                                                 const float* __restrict__ Wg,
                                                 unsigned short* __restrict__ hg) {
    __shared__ unsigned short wlds[OO * HH];      // 16 KiB
    int t = threadIdx.x;
    #pragma unroll
    for (int it = 0; it < 4; ++it) {
        int cid = t + it * 256;          // 1024 chunks
        int o = cid >> 4, c = cid & 15;
        int boff = (o * 256 + c * 16) ^ ((o & 7) << 4);
        const float4* p = (const float4*)(Wg + (long)o * HH + c * 8);
        float4 a = p[0], b = p[1];
        short8v w;
        w[0]=(short)f2bf(a.x); w[1]=(short)f2bf(a.y); w[2]=(short)f2bf(a.z); w[3]=(short)f2bf(a.w);
        w[4]=(short)f2bf(b.x); w[5]=(short)f2bf(b.y); w[6]=(short)f2bf(b.z); w[7]=(short)f2bf(b.w);
        *(short8v*)((char*)(&wlds[0]) + boff) = w;
    }
    __syncthreads();

    int wave = t >> 6, lane = t & 63;
    int rowbase = blockIdx.x * 128 + wave * 32;
    int lr = lane & 15;
    int kq = (lane >> 4) * 8;
    int r0 = rowbase + lr, r1 = r0 + 16;
    int cr0 = (r0 < NN) ? r0 : 0;
    int cr1 = (r1 < NN) ? r1 : 0;

    f32x4 acc[2][4];
    #pragma unroll
    for (int i = 0; i < 2; ++i)
        #pragma unroll
        for (int j = 0; j < 4; ++j) { f32x4 z = {0.f,0.f,0.f,0.f}; acc[i][j] = z; }

    #pragma unroll
    for (int k0 = 0; k0 < HH; k0 += 32) {
        int kk = k0 + kq;
        short8v a0 = *(const short8v*)(h + (long)cr0 * HH + kk);
        short8v a1 = *(const short8v*)(h + (long)cr1 * HH + kk);
        #pragma unroll
        for (int nb = 0; nb < 4; ++nb) {
            int o = nb * 16 + lr;
            int boff = (o * 256 + kk * 2) ^ ((o & 7) << 4);
            short8v b = *(const short8v*)((const char*)(&wlds[0]) + boff);
            acc[0][nb] = __builtin_amdgcn_mfma_f32_16x16x32_bf16(a0, b, acc[0][nb], 0, 0, 0);
            acc[1][nb] = __builtin_amdgcn_mfma_f32_16x16x32_bf16(a1, b, acc[1][nb], 0, 0, 0);
        }
    }
    int q = lane >> 4;
    #pragma unroll
    for (int rh = 0; rh < 2; ++rh)
        #pragma unroll
        for (int nb = 0; nb < 4; ++nb)
            #pragma unroll
            for (int r = 0; r < 4; ++r) {
                int row = rowbase + rh * 16 + q * 4 + r;
                if (row < NN) hg[(long)row * OO + nb * 16 + lr] = f2bf(acc[rh][nb][r]);
            }
}

// ---------------- K5b: alpha_src/alpha_dst dots ----------------
__global__ __launch_bounds__(256) void k_alpha(const unsigned short* __restrict__ hg,
                                               const float* __restrict__ asrc,
                                               const float* __restrict__ adst,
                                               float* __restrict__ al_s,
                                               float* __restrict__ al_d) {
    __shared__ float sa[OO], sd[OO];
    int t = threadIdx.x;
    if (t < OO) { sa[t] = asrc[t]; sd[t] = adst[t]; }
    __syncthreads();
    int i = blockIdx.x * 256 + t;
    if (i >= NN) return;
    float s = 0.f, d = 0.f;
    #pragma unroll
    for (int o = 0; o < OO; ++o) {
        float v = bf2f(hg[(long)i * OO + o]);
        s += v * sa[o];
        d += v * sd[o];
    }
    al_s[i] = s;
    al_d[i] = d;
}

// ---------------- K6: edge logits -> exp, denominators ----------------
__global__ __launch_bounds__(256) void k_edge(const int* __restrict__ ap_src,
                                              const int* __restrict__ meta_dst,
                                              const int* __restrict__ perm,
                                              const float* __restrict__ as_,
                                              const float* __restrict__ ad_,
                                              float* __restrict__ exp_p,
                                              float* __restrict__ exp_n,
                                              float* __restrict__ den_p,
                                              float* __restrict__ den_n) {
    int e = blockIdx.x * 256 + threadIdx.x;
    if (e >= EE + NN) return;
    int s, d;
    if (e < EE) { s = ap_src[e]; d = meta_dst[e]; }
    else        { s = e - EE; d = s; }
    float ep = as_[s] + ad_[d];
    ep = (ep >= 0.f) ? ep : 0.2f * ep;
    float xp = expf(ep);
    exp_p[e] = xp;
    atomicAdd(&den_p[d], xp);
    int ps = perm[s], pd = perm[d];
    float en = as_[ps] + ad_[pd];
    en = (en >= 0.f) ? en : 0.2f * en;
    float xn = expf(en);
    exp_n[e] = xn;
    atomicAdd(&den_n[d], xn);
}

// ---------------- K7: GAT weighted scatter (pos + neg) ----------------
// one wave per edge, lane = output dim
__global__ __launch_bounds__(256) void k_scatter(const int* __restrict__ ap_src,
                                                 const int* __restrict__ meta_dst,
                                                 const int* __restrict__ perm,
                                                 const unsigned short* __restrict__ hg,
                                                 const float* __restrict__ exp_p,
                                                 const float* __restrict__ exp_n,
                                                 const float* __restrict__ den_p,
                                                 const float* __restrict__ den_n,
                                                 float* __restrict__ out_pos,
                                                 float* __restrict__ out_neg) {
    int e = blockIdx.x * 4 + (threadIdx.x >> 6);
    if (e >= EE + NN) return;
    int lane = threadIdx.x & 63;
    int s, d;
    if (e < EE) { s = ap_src[e]; d = meta_dst[e]; }
    else        { s = e - EE; d = s; }
    float cp = exp_p[e] / den_p[d];
    float cn = exp_n[e] / den_n[d];
    int ps = perm[s];
    float hv = bf2f(hg[(long)s * OO + lane]);
    float hn = bf2f(hg[(long)ps * OO + lane]);
    atomicAdd(out_pos + (long)d * OO + lane, cp * hv);
    atomicAdd(out_neg + (long)d * OO + lane, cn * hn);
}

// ---------------- K8: bias + PReLU + summary mean ----------------
__global__ __launch_bounds__(256) void k_final(float* __restrict__ out,
                                               const float* __restrict__ gb,
                                               const float* __restrict__ prelu_a) {
    float a = prelu_a[0];
    int j = threadIdx.x & 63;
    int sub = threadIdx.x >> 6;      // 0..3
    float bias = gb[j];
    long base = (long)blockIdx.x * 64;
    float acc = 0.f;
    for (int rr = sub; rr < 64; rr += 4) {
        long row = base + rr;
        if (row >= NN) break;
        long idx = row * OO + j;
        float vp = out[idx] + bias;
        vp = (vp >= 0.f) ? vp : a * vp;
        out[idx] = vp;
        acc += vp;
        long nidx = (long)NN * OO + idx;
        float vn = out[nidx] + bias;
        vn = (vn >= 0.f) ? vn : a * vn;
        out[nidx] = vn;
    }
    __shared__ float red[4][OO];
    red[sub][j] = acc;
    __syncthreads();
    if (sub == 0) {
        float ttl = red[0][j] + red[1][j] + red[2][j] + red[3][j];
        atomicAdd(out + 2L * NN * OO + j, ttl * (1.0f / NN));
    }
}

extern "C" void kernel_launch(void* const* d_in, const int* in_sizes, int n_in,
                              void* d_out, int out_size, void* d_ws, size_t ws_size,
                              hipStream_t stream) {
    const float* x_author = (const float*)d_in[0];
    const float* x_paper  = (const float*)d_in[1];
    const float* sage_Wl  = (const float*)d_in[2];
    const float* sage_Wr  = (const float*)d_in[3];
    const float* sage_b   = (const float*)d_in[4];
    const float* gat_W    = (const float*)d_in[5];
    const float* gat_as   = (const float*)d_in[6];
    const float* gat_ad   = (const float*)d_in[7];
    const float* gat_b    = (const float*)d_in[8];
    const float* prelu_a  = (const float*)d_in[9];
    const int*   edge_ap  = (const int*)d_in[10];
    const int*   edge_pa  = (const int*)d_in[11];
    const int*   perm     = (const int*)d_in[12];

    char* ws = (char*)d_ws;
    float* agg                 = (float*)(ws + 0);               // N*D f32   = 51,200,000
    int*   cnt                 = (int*)  (ws + 51200000);        // N  i32    =    400,000
    unsigned long long* p2a    = (unsigned long long*)(ws + 51600000); // N u64 =  800,000
    float* den_p               = (float*)(ws + 52400000);        // N f32
    float* den_n               = (float*)(ws + 52800000);        // N f32
    // --- zeroed region ends at 53,200,000 ---
    unsigned short* h          = (unsigned short*)(ws + 53200000);  // N*128 bf16 = 25,600,000
    unsigned short* hg         = (unsigned short*)(ws + 78800000);  // N*64 bf16  = 12,800,000
    int*   meta                = (int*)  (ws + 91600000);        // E i32      =  3,200,000
    float* al_s                = (float*)(ws + 94800000);        // N f32
    float* al_d                = (float*)(ws + 95200000);        // N f32
    float* exp_p               = (float*)(ws + 95600000);        // (E+N) f32  =  3,600,000
    float* exp_n               = (float*)(ws + 99200000);        // (E+N) f32
    // total = 102,800,000 bytes

    hipMemsetAsync(d_ws, 0, 53200000, stream);
    hipMemsetAsync(d_out, 0, (size_t)out_size * sizeof(float), stream);

    const float* Wl = sage_Wl + 3 * HH * DD;   // [l=1][et=1]
    const float* Wr = sage_Wr + 3 * HH * DD;
    const float* sb = sage_b  + 3 * HH;

    k_p2a<<<(EE + 255) / 256, 256, 0, stream>>>(edge_pa, edge_pa + EE, p2a);
    k_meta<<<(EE + 255) / 256, 256, 0, stream>>>(edge_ap + EE, p2a, meta);
    k_sageagg<<<(int)(((long)EE * 32 + 255) / 256), 256, 0, stream>>>(edge_pa, edge_pa + EE,
                                                                      x_paper, agg, cnt);
    k_sagegemm<<<(NN + 127) / 128, 256, 0, stream>>>(agg, cnt, x_author, Wl, Wr, sb, h);
    k_gatgemm<<<(NN + 127) / 128, 256, 0, stream>>>(h, gat_W, hg);
    k_alpha<<<(NN + 255) / 256, 256, 0, stream>>>(hg, gat_as, gat_ad, al_s, al_d);
    k_edge<<<(EE + NN + 255) / 256, 256, 0, stream>>>(edge_ap, meta, perm, al_s, al_d,
                                                      exp_p, exp_n, den_p, den_n);
    k_scatter<<<(EE + NN + 3) / 4, 256, 0, stream>>>(edge_ap, meta, perm, hg,
                                                     exp_p, exp_n, den_p, den_n,
                                                     (float*)d_out, (float*)d_out + (long)NN * OO);
    k_final<<<(NN + 63) / 64, 256, 0, stream>>>((float*)d_out, gat_b, prelu_a);
}

// Round 2
// 691.862 us; speedup vs baseline: 2.8919x; 2.8919x over previous
//
#include <hip/hip_runtime.h>
#include <stdint.h>

#define NN 100000
#define EE 800000
#define DD 128
#define HH 128
#define OO 64

#define SCAN_N 200000          // concatenated counts: [0,1e5) = pa, [1e5,2e5) = meta
#define SCAN_B 782             // ceil(200000/256)
#define TOTAL_SLOTS 1700000    // 800000 pa + 900000 meta

typedef __attribute__((ext_vector_type(8))) short short8v;   // 8 x bf16 fragment
typedef __attribute__((ext_vector_type(4))) float f32x4;     // MFMA accumulator

__device__ __forceinline__ unsigned short f2bf(float f) {
    union { float f; unsigned int u; } v; v.f = f;
    unsigned int u = v.u;
    u = (u + 0x7fffu + ((u >> 16) & 1u)) >> 16;   // RNE
    return (unsigned short)u;
}
__device__ __forceinline__ float bf2f(unsigned short b) {
    union { unsigned int u; float f; } v; v.u = ((unsigned int)b) << 16;
    return v.f;
}

// ---------------- K1: p2a last-write-wins scatter + pa in-degree histogram ----------------
__global__ __launch_bounds__(256) void k_p2a(const int* __restrict__ pa_src,
                                             const int* __restrict__ pa_dst,
                                             unsigned long long* __restrict__ p2a,
                                             int* __restrict__ cnt2) {
    int e = blockIdx.x * 256 + threadIdx.x;
    if (e >= EE) return;
    int d = pa_dst[e];
    unsigned long long key = ((unsigned long long)(unsigned int)e << 32) | (unsigned int)d;
    atomicMax(&p2a[pa_src[e]], key);
    atomicAdd(&cnt2[d], 1);
}

// ---------------- K2: meta_dst + meta in-degree histogram (incl. self loops) ----------------
__global__ __launch_bounds__(256) void k_meta(const int* __restrict__ ap_dst,
                                              const unsigned long long* __restrict__ p2a,
                                              int* __restrict__ meta_dst,
                                              int* __restrict__ cnt2) {
    int e = blockIdx.x * 256 + threadIdx.x;
    if (e < EE) {
        int d = (int)(p2a[ap_dst[e]] & 0xffffffffull);
        meta_dst[e] = d;
        atomicAdd(&cnt2[NN + d], 1);
    } else if (e < EE + NN) {
        atomicAdd(&cnt2[NN + (e - EE)], 1);   // self loop
    }
}

// ---------------- K3: exclusive scan of cnt2 (3 stages) ----------------
__global__ __launch_bounds__(256) void k_scan_block(const int* __restrict__ cnt2,
                                                    int* __restrict__ rs,
                                                    int* __restrict__ bsum) {
    __shared__ int sh[256];
    int t = threadIdx.x;
    int id = blockIdx.x * 256 + t;
    int v = (id < SCAN_N) ? cnt2[id] : 0;
    sh[t] = v;
    __syncthreads();
    #pragma unroll
    for (int off = 1; off < 256; off <<= 1) {
        int x = (t >= off) ? sh[t - off] : 0;
        __syncthreads();
        sh[t] += x;
        __syncthreads();
    }
    int incl = sh[t];
    if (id <= SCAN_N) { }            // rs has SCAN_N+1 entries; last written in scan_add
    if (id < SCAN_N) rs[id] = incl - v;
    if (t == 255) bsum[blockIdx.x] = incl;
}

__global__ __launch_bounds__(1024) void k_scan_top(int* __restrict__ bsum) {
    __shared__ int sh[1024];
    int t = threadIdx.x;
    int v = (t < SCAN_B) ? bsum[t] : 0;
    sh[t] = v;
    __syncthreads();
    #pragma unroll
    for (int off = 1; off < 1024; off <<= 1) {
        int x = (t >= off) ? sh[t - off] : 0;
        __syncthreads();
        sh[t] += x;
        __syncthreads();
    }
    if (t < SCAN_B) bsum[t] = sh[t] - v;   // exclusive
}

__global__ __launch_bounds__(256) void k_scan_add(int* __restrict__ rs,
                                                  const int* __restrict__ bsum) {
    int id = blockIdx.x * 256 + threadIdx.x;
    if (id < SCAN_N) rs[id] += bsum[id >> 8];
    if (id == 0) rs[SCAN_N] = TOTAL_SLOTS;
}

// ---------------- K4: CSR fill (pa edges, meta edges, self loops) ----------------
__global__ __launch_bounds__(256) void k_fill(const int* __restrict__ pa_src,
                                              const int* __restrict__ pa_dst,
                                              const int* __restrict__ ap_src,
                                              const int* __restrict__ meta_dst,
                                              const int* __restrict__ rs,
                                              int* __restrict__ cur2,
                                              int* __restrict__ col_src,
                                              int* __restrict__ col_eid) {   // col_eid indexed by (slot-800000)
    int id = blockIdx.x * 256 + threadIdx.x;
    if (id < EE) {                       // pa edge
        int d = pa_dst[id];
        int pos = atomicAdd(&cur2[d], 1);
        col_src[rs[d] + pos] = pa_src[id];
    } else if (id < 2 * EE) {            // meta edge
        int e = id - EE;
        int d = meta_dst[e];
        int pos = 1 + atomicAdd(&cur2[NN + d], 1);   // slot 0 reserved for self loop
        int idx = rs[NN + d] + pos;
        col_src[idx] = ap_src[e];
        col_eid[idx - EE] = e;
    } else if (id < 2 * EE + NN) {       // self loop
        int d = id - 2 * EE;
        int idx = rs[NN + d];
        col_src[idx] = d;
        col_eid[idx - EE] = EE + d;
    }
}

// ---------------- K5: SAGE mean-aggregate (gather), writes mean as bf16 ----------------
// one wave per dst row, lane = 2 dims (float2)
__global__ __launch_bounds__(256) void k_sage_gather(const int* __restrict__ rs,
                                                     const int* __restrict__ col_src,
                                                     const float* __restrict__ x_paper,
                                                     unsigned short* __restrict__ mean_bf) {
    long gid = (long)blockIdx.x * 256 + threadIdx.x;
    int d = (int)(gid >> 6);
    if (d >= NN) return;
    int lane = (int)(gid & 63);
    int ks = rs[d], ke = rs[d + 1];
    float ax = 0.f, ay = 0.f;
    for (int i = ks; i < ke; ++i) {
        int s = col_src[i];
        float2 v = ((const float2*)(x_paper + (long)s * DD))[lane];
        ax += v.x; ay += v.y;
    }
    float sc = 1.0f / fmaxf((float)(ke - ks), 1.0f);
    ushort2 w;
    w.x = f2bf(ax * sc);
    w.y = f2bf(ay * sc);
    ((ushort2*)(mean_bf + (long)d * DD))[lane] = w;
}

// ---------------- K6: h = lrelu(mean@Wl^T + x@Wr^T + b), store bf16 ----------------
__global__ __launch_bounds__(256) void k_sagegemm(const unsigned short* __restrict__ mean_bf,
                                                  const float* __restrict__ xa,
                                                  const float* __restrict__ Wl,
                                                  const float* __restrict__ Wr,
                                                  const float* __restrict__ sb,
                                                  unsigned short* __restrict__ h) {
    __shared__ unsigned short wlds[2][HH * DD];   // 64 KiB, bf16, XOR-swizzled
    int t = threadIdx.x;
    #pragma unroll
    for (int it = 0; it < 8; ++it) {
        int cid = t + it * 256;          // 2048 chunks of 8 elems
        int o = cid >> 4, c = cid & 15;
        int boff = (o * 256 + c * 16) ^ ((o & 7) << 4);
        {
            const float4* p = (const float4*)(Wl + (long)o * DD + c * 8);
            float4 a = p[0], b = p[1];
            short8v w;
            w[0]=(short)f2bf(a.x); w[1]=(short)f2bf(a.y); w[2]=(short)f2bf(a.z); w[3]=(short)f2bf(a.w);
            w[4]=(short)f2bf(b.x); w[5]=(short)f2bf(b.y); w[6]=(short)f2bf(b.z); w[7]=(short)f2bf(b.w);
            *(short8v*)((char*)(&wlds[0][0]) + boff) = w;
        }
        {
            const float4* p = (const float4*)(Wr + (long)o * DD + c * 8);
            float4 a = p[0], b = p[1];
            short8v w;
            w[0]=(short)f2bf(a.x); w[1]=(short)f2bf(a.y); w[2]=(short)f2bf(a.z); w[3]=(short)f2bf(a.w);
            w[4]=(short)f2bf(b.x); w[5]=(short)f2bf(b.y); w[6]=(short)f2bf(b.z); w[7]=(short)f2bf(b.w);
            *(short8v*)((char*)(&wlds[1][0]) + boff) = w;
        }
    }
    __syncthreads();

    int wave = t >> 6, lane = t & 63;
    int rowbase = blockIdx.x * 128 + wave * 32;
    int lr = lane & 15;
    int kq = (lane >> 4) * 8;
    int r0 = rowbase + lr, r1 = r0 + 16;
    int cr0 = (r0 < NN) ? r0 : 0;
    int cr1 = (r1 < NN) ? r1 : 0;

    f32x4 acc[2][8];
    #pragma unroll
    for (int i = 0; i < 2; ++i)
        #pragma unroll
        for (int j = 0; j < 8; ++j) { f32x4 z = {0.f,0.f,0.f,0.f}; acc[i][j] = z; }

    #pragma unroll
    for (int k0 = 0; k0 < DD; k0 += 32) {
        int kk = k0 + kq;
        short8v am0 = *(const short8v*)(mean_bf + (long)cr0 * DD + kk);
        short8v am1 = *(const short8v*)(mean_bf + (long)cr1 * DD + kk);
        const float4* q0 = (const float4*)(xa + (long)cr0 * DD + kk);
        const float4* q1 = (const float4*)(xa + (long)cr1 * DD + kk);
        float4 a0 = q0[0], b0 = q0[1], a1 = q1[0], b1 = q1[1];
        short8v ax0, ax1;
        ax0[0]=(short)f2bf(a0.x); ax0[1]=(short)f2bf(a0.y); ax0[2]=(short)f2bf(a0.z); ax0[3]=(short)f2bf(a0.w);
        ax0[4]=(short)f2bf(b0.x); ax0[5]=(short)f2bf(b0.y); ax0[6]=(short)f2bf(b0.z); ax0[7]=(short)f2bf(b0.w);
        ax1[0]=(short)f2bf(a1.x); ax1[1]=(short)f2bf(a1.y); ax1[2]=(short)f2bf(a1.z); ax1[3]=(short)f2bf(a1.w);
        ax1[4]=(short)f2bf(b1.x); ax1[5]=(short)f2bf(b1.y); ax1[6]=(short)f2bf(b1.z); ax1[7]=(short)f2bf(b1.w);
        #pragma unroll
        for (int nb = 0; nb < 8; ++nb) {
            int o = nb * 16 + lr;
            int boff = (o * 256 + kk * 2) ^ ((o & 7) << 4);
            short8v bl = *(const short8v*)((const char*)(&wlds[0][0]) + boff);
            short8v br = *(const short8v*)((const char*)(&wlds[1][0]) + boff);
            acc[0][nb] = __builtin_amdgcn_mfma_f32_16x16x32_bf16(am0, bl, acc[0][nb], 0, 0, 0);
            acc[1][nb] = __builtin_amdgcn_mfma_f32_16x16x32_bf16(am1, bl, acc[1][nb], 0, 0, 0);
            acc[0][nb] = __builtin_amdgcn_mfma_f32_16x16x32_bf16(ax0, br, acc[0][nb], 0, 0, 0);
            acc[1][nb] = __builtin_amdgcn_mfma_f32_16x16x32_bf16(ax1, br, acc[1][nb], 0, 0, 0);
        }
    }
    int q = lane >> 4;
    #pragma unroll
    for (int rh = 0; rh < 2; ++rh) {
        #pragma unroll
        for (int nb = 0; nb < 8; ++nb) {
            int col = nb * 16 + lr;
            float bias = sb[col];
            #pragma unroll
            for (int r = 0; r < 4; ++r) {
                int row = rowbase + rh * 16 + q * 4 + r;
                if (row < NN) {
                    float v = acc[rh][nb][r] + bias;
                    v = (v >= 0.f) ? v : 0.01f * v;
                    h[(long)row * HH + col] = f2bf(v);
                }
            }
        }
    }
}

// ---------------- K7: hg = h @ gatW^T, store bf16 ----------------
__global__ __launch_bounds__(256) void k_gatgemm(const unsigned short* __restrict__ h,
                                                 const float* __restrict__ Wg,
                                                 unsigned short* __restrict__ hg) {
    __shared__ unsigned short wlds[OO * HH];      // 16 KiB
    int t = threadIdx.x;
    #pragma unroll
    for (int it = 0; it < 4; ++it) {
        int cid = t + it * 256;          // 1024 chunks
        int o = cid >> 4, c = cid & 15;
        int boff = (o * 256 + c * 16) ^ ((o & 7) << 4);
        const float4* p = (const float4*)(Wg + (long)o * HH + c * 8);
        float4 a = p[0], b = p[1];
        short8v w;
        w[0]=(short)f2bf(a.x); w[1]=(short)f2bf(a.y); w[2]=(short)f2bf(a.z); w[3]=(short)f2bf(a.w);
        w[4]=(short)f2bf(b.x); w[5]=(short)f2bf(b.y); w[6]=(short)f2bf(b.z); w[7]=(short)f2bf(b.w);
        *(short8v*)((char*)(&wlds[0]) + boff) = w;
    }
    __syncthreads();

    int wave = t >> 6, lane = t & 63;
    int rowbase = blockIdx.x * 128 + wave * 32;
    int lr = lane & 15;
    int kq = (lane >> 4) * 8;
    int r0 = rowbase + lr, r1 = r0 + 16;
    int cr0 = (r0 < NN) ? r0 : 0;
    int cr1 = (r1 < NN) ? r1 : 0;

    f32x4 acc[2][4];
    #pragma unroll
    for (int i = 0; i < 2; ++i)
        #pragma unroll
        for (int j = 0; j < 4; ++j) { f32x4 z = {0.f,0.f,0.f,0.f}; acc[i][j] = z; }

    #pragma unroll
    for (int k0 = 0; k0 < HH; k0 += 32) {
        int kk = k0 + kq;
        short8v a0 = *(const short8v*)(h + (long)cr0 * HH + kk);
        short8v a1 = *(const short8v*)(h + (long)cr1 * HH + kk);
        #pragma unroll
        for (int nb = 0; nb < 4; ++nb) {
            int o = nb * 16 + lr;
            int boff = (o * 256 + kk * 2) ^ ((o & 7) << 4);
            short8v b = *(const short8v*)((const char*)(&wlds[0]) + boff);
            acc[0][nb] = __builtin_amdgcn_mfma_f32_16x16x32_bf16(a0, b, acc[0][nb], 0, 0, 0);
            acc[1][nb] = __builtin_amdgcn_mfma_f32_16x16x32_bf16(a1, b, acc[1][nb], 0, 0, 0);
        }
    }
    int q = lane >> 4;
    #pragma unroll
    for (int rh = 0; rh < 2; ++rh)
        #pragma unroll
        for (int nb = 0; nb < 4; ++nb)
            #pragma unroll
            for (int r = 0; r < 4; ++r) {
                int row = rowbase + rh * 16 + q * 4 + r;
                if (row < NN) hg[(long)row * OO + nb * 16 + lr] = f2bf(acc[rh][nb][r]);
            }
}

// ---------------- K8: alpha_src/alpha_dst dots ----------------
__global__ __launch_bounds__(256) void k_alpha(const unsigned short* __restrict__ hg,
                                               const float* __restrict__ asrc,
                                               const float* __restrict__ adst,
                                               float* __restrict__ al_s,
                                               float* __restrict__ al_d) {
    __shared__ float sa[OO], sd[OO];
    int t = threadIdx.x;
    if (t < OO) { sa[t] = asrc[t]; sd[t] = adst[t]; }
    __syncthreads();
    int i = blockIdx.x * 256 + t;
    if (i >= NN) return;
    float s = 0.f, d = 0.f;
    #pragma unroll
    for (int o = 0; o < OO; ++o) {
        float v = bf2f(hg[(long)i * OO + o]);
        s += v * sa[o];
        d += v * sd[o];
    }
    al_s[i] = s;
    al_d[i] = d;
}

// ---------------- K9: per-edge exp logits (store only, no atomics) ----------------
__global__ __launch_bounds__(256) void k_edge(const int* __restrict__ ap_src,
                                              const int* __restrict__ meta_dst,
                                              const int* __restrict__ perm,
                                              const float* __restrict__ as_,
                                              const float* __restrict__ ad_,
                                              float* __restrict__ exp_p,
                                              float* __restrict__ exp_n) {
    int e = blockIdx.x * 256 + threadIdx.x;
    if (e >= EE + NN) return;
    int s, d;
    if (e < EE) { s = ap_src[e]; d = meta_dst[e]; }
    else        { s = e - EE; d = s; }
    float ep = as_[s] + ad_[d];
    ep = (ep >= 0.f) ? ep : 0.2f * ep;
    exp_p[e] = expf(ep);
    int ps = perm[s], pd = perm[d];
    float en = as_[ps] + ad_[pd];
    en = (en >= 0.f) ? en : 0.2f * en;
    exp_n[e] = expf(en);
}

// ---------------- K10: GAT softmax + aggregate (gather), bias+PReLU fused ----------------
// one wave per dst row, lane = output dim
__global__ __launch_bounds__(256) void k_gat_gather(const int* __restrict__ rs,
                                                    const int* __restrict__ col_src,
                                                    const int* __restrict__ col_eid,   // indexed by slot-EE
                                                    const int* __restrict__ perm,
                                                    const unsigned short* __restrict__ hg,
                                                    const float* __restrict__ exp_p,
                                                    const float* __restrict__ exp_n,
                                                    const float* __restrict__ gb,
                                                    const float* __restrict__ prelu_a,
                                                    float* __restrict__ out_pos,
                                                    float* __restrict__ out_neg) {
    long gid = (long)blockIdx.x * 256 + threadIdx.x;
    int d = (int)(gid >> 6);
    if (d >= NN) return;
    int j = (int)(gid & 63);
    int ks = rs[NN + d], ke = rs[NN + d + 1];
    float denp = 0.f, denn = 0.f;
    for (int i = ks; i < ke; ++i) {
        int em = col_eid[i - EE];
        denp += exp_p[em];
        denn += exp_n[em];
    }
    float accp = 0.f, accn = 0.f;
    for (int i = ks; i < ke; ++i) {
        int em = col_eid[i - EE];
        int s = col_src[i];
        accp += exp_p[em] * bf2f(hg[(long)s * OO + j]);
        int ps = perm[s];
        accn += exp_n[em] * bf2f(hg[(long)ps * OO + j]);
    }
    float bias = gb[j];
    float a = prelu_a[0];
    float vp = accp / denp + bias;
    vp = (vp >= 0.f) ? vp : a * vp;
    out_pos[(long)d * OO + j] = vp;
    float vn = accn / denn + bias;
    vn = (vn >= 0.f) ? vn : a * vn;
    out_neg[(long)d * OO + j] = vn;
}

// ---------------- K11: summary mean over pos rows ----------------
__global__ __launch_bounds__(256) void k_summary(const float* __restrict__ out_pos,
                                                 float* __restrict__ summary) {
    int t = threadIdx.x;
    int j = t & 63, sub = t >> 6;
    float acc = 0.f;
    for (int row = blockIdx.x * 4 + sub; row < NN; row += 256 * 4) {
        acc += out_pos[(long)row * OO + j];
    }
    __shared__ float red[4][OO];
    red[sub][j] = acc;
    __syncthreads();
    if (sub == 0) {
        float ttl = red[0][j] + red[1][j] + red[2][j] + red[3][j];
        atomicAdd(summary + j, ttl * (1.0f / NN));
    }
}

extern "C" void kernel_launch(void* const* d_in, const int* in_sizes, int n_in,
                              void* d_out, int out_size, void* d_ws, size_t ws_size,
                              hipStream_t stream) {
    const float* x_author = (const float*)d_in[0];
    const float* x_paper  = (const float*)d_in[1];
    const float* sage_Wl  = (const float*)d_in[2];
    const float* sage_Wr  = (const float*)d_in[3];
    const float* sage_b   = (const float*)d_in[4];
    const float* gat_W    = (const float*)d_in[5];
    const float* gat_as   = (const float*)d_in[6];
    const float* gat_ad   = (const float*)d_in[7];
    const float* gat_b    = (const float*)d_in[8];
    const float* prelu_a  = (const float*)d_in[9];
    const int*   edge_ap  = (const int*)d_in[10];
    const int*   edge_pa  = (const int*)d_in[11];
    const int*   perm     = (const int*)d_in[12];

    char* ws = (char*)d_ws;
    unsigned long long* p2a = (unsigned long long*)(ws + 0);       //   800,000
    int*   cnt2      = (int*)(ws + 800000);                        //   800,000
    int*   cur2      = (int*)(ws + 1600000);                       //   800,000
    // --- zeroed region ends at 2,400,000 ---
    int*   rs        = (int*)(ws + 2400000);                       //   800,016 (200001 ints)
    int*   bsum      = (int*)(ws + 3200016);                       //     4,096
    int*   meta      = (int*)(ws + 3204112);                       // 3,200,000
    int*   col_src   = (int*)(ws + 6404112);                       // 6,800,000 (1.7M slots)
    int*   col_eid   = (int*)(ws + 13204112);                      // 3,600,000 (meta slots only)
    float* exp_p     = (float*)(ws + 16804112);                    // 3,600,000
    float* exp_n     = (float*)(ws + 20404112);                    // 3,600,000
    float* al_s      = (float*)(ws + 24004112);                    //   400,000
    float* al_d      = (float*)(ws + 24404112);                    //   400,000
    unsigned short* mean_bf = (unsigned short*)(ws + 24804112);    // 25,600,000
    unsigned short* h       = (unsigned short*)(ws + 50404112);    // 25,600,000
    unsigned short* hg      = (unsigned short*)(ws + 76004112);    // 12,800,000
    // total = 88,804,112 bytes

    hipMemsetAsync(d_ws, 0, 2400000, stream);
    hipMemsetAsync((char*)d_out + (size_t)2 * NN * OO * sizeof(float), 0,
                   OO * sizeof(float), stream);

    const float* Wl = sage_Wl + 3 * HH * DD;   // [l=1][et=1]
    const float* Wr = sage_Wr + 3 * HH * DD;
    const float* sb = sage_b  + 3 * HH;

    k_p2a<<<(EE + 255) / 256, 256, 0, stream>>>(edge_pa, edge_pa + EE, p2a, cnt2);
    k_meta<<<(EE + NN + 255) / 256, 256, 0, stream>>>(edge_ap + EE, p2a, meta, cnt2);
    k_scan_block<<<SCAN_B, 256, 0, stream>>>(cnt2, rs, bsum);
    k_scan_top<<<1, 1024, 0, stream>>>(bsum);
    k_scan_add<<<SCAN_B, 256, 0, stream>>>(rs, bsum);
    k_fill<<<(2 * EE + NN + 255) / 256, 256, 0, stream>>>(edge_pa, edge_pa + EE,
                                                          edge_ap, meta, rs, cur2,
                                                          col_src, col_eid - EE + EE /*dummy*/);
    // note: col_eid is indexed by (slot-EE) inside kernels; pass base directly
    k_sage_gather<<<(NN * 64 + 255) / 256, 256, 0, stream>>>(rs, col_src, x_paper, mean_bf);
    k_sagegemm<<<(NN + 127) / 128, 256, 0, stream>>>(mean_bf, x_author, Wl, Wr, sb, h);
    k_gatgemm<<<(NN + 127) / 128, 256, 0, stream>>>(h, gat_W, hg);
    k_alpha<<<(NN + 255) / 256, 256, 0, stream>>>(hg, gat_as, gat_ad, al_s, al_d);
    k_edge<<<(EE + NN + 255) / 256, 256, 0, stream>>>(edge_ap, meta, perm, al_s, al_d,
                                                      exp_p, exp_n);
    k_gat_gather<<<(NN * 64 + 255) / 256, 256, 0, stream>>>(rs, col_src, col_eid, perm, hg,
                                                            exp_p, exp_n, gat_b, prelu_a,
                                                            (float*)d_out,
                                                            (float*)d_out + (long)NN * OO);
    k_summary<<<256, 256, 0, stream>>>((float*)d_out, (float*)d_out + 2L * NN * OO);
}

// Round 3
// 447.563 us; speedup vs baseline: 4.4704x; 1.5458x over previous
//
#include <hip/hip_runtime.h>
#include <stdint.h>

#define NN 100000
#define EE 800000
#define DD 128
#define HH 128
#define OO 64

#define SCAN_N 200000          // concatenated counts: [0,1e5) = pa, [1e5,2e5) = meta
#define SCAN_B 782             // ceil(200000/256)
#define TOTAL_SLOTS 1700000    // 800000 pa + 900000 meta (incl. self loops)

typedef __attribute__((ext_vector_type(8))) short short8v;   // 8 x bf16 fragment
typedef __attribute__((ext_vector_type(4))) float f32x4;     // MFMA accumulator

__device__ __forceinline__ unsigned short f2bf(float f) {
    union { float f; unsigned int u; } v; v.f = f;
    unsigned int u = v.u;
    u = (u + 0x7fffu + ((u >> 16) & 1u)) >> 16;   // RNE
    return (unsigned short)u;
}
__device__ __forceinline__ float bf2f(unsigned short b) {
    union { unsigned int u; float f; } v; v.u = ((unsigned int)b) << 16;
    return v.f;
}

// ---------------- K0: x_paper -> bf16 ----------------
__global__ __launch_bounds__(256) void k_cast(const float* __restrict__ x,
                                              unsigned short* __restrict__ xbf) {
    long i = (long)blockIdx.x * 256 + threadIdx.x;   // one float4 per thread
    if (i >= (long)NN * DD / 4) return;
    float4 v = ((const float4*)x)[i];
    ushort4 w;
    w.x = f2bf(v.x); w.y = f2bf(v.y); w.z = f2bf(v.z); w.w = f2bf(v.w);
    ((ushort4*)xbf)[i] = w;
}

// ---------------- K1: p2a last-write-wins scatter + pa in-degree histogram ----------------
__global__ __launch_bounds__(256) void k_p2a(const int* __restrict__ pa_src,
                                             const int* __restrict__ pa_dst,
                                             unsigned long long* __restrict__ p2a,
                                             int* __restrict__ cnt2) {
    int e = blockIdx.x * 256 + threadIdx.x;
    if (e >= EE) return;
    int d = pa_dst[e];
    unsigned long long key = ((unsigned long long)(unsigned int)e << 32) | (unsigned int)d;
    atomicMax(&p2a[pa_src[e]], key);
    atomicAdd(&cnt2[d], 1);
}

// ---------------- K2: meta_dst + meta in-degree histogram (incl. self loops) ----------------
__global__ __launch_bounds__(256) void k_meta(const int* __restrict__ ap_dst,
                                              const unsigned long long* __restrict__ p2a,
                                              int* __restrict__ meta_dst,
                                              int* __restrict__ cnt2) {
    int e = blockIdx.x * 256 + threadIdx.x;
    if (e < EE) {
        int d = (int)(p2a[ap_dst[e]] & 0xffffffffull);
        meta_dst[e] = d;
        atomicAdd(&cnt2[NN + d], 1);
    } else if (e < EE + NN) {
        atomicAdd(&cnt2[NN + (e - EE)], 1);   // self loop
    }
}

// ---------------- K3: exclusive scan of cnt2 (3 stages) ----------------
__global__ __launch_bounds__(256) void k_scan_block(const int* __restrict__ cnt2,
                                                    int* __restrict__ rs,
                                                    int* __restrict__ bsum) {
    __shared__ int sh[256];
    int t = threadIdx.x;
    int id = blockIdx.x * 256 + t;
    int v = (id < SCAN_N) ? cnt2[id] : 0;
    sh[t] = v;
    __syncthreads();
    #pragma unroll
    for (int off = 1; off < 256; off <<= 1) {
        int x = (t >= off) ? sh[t - off] : 0;
        __syncthreads();
        sh[t] += x;
        __syncthreads();
    }
    int incl = sh[t];
    if (id < SCAN_N) rs[id] = incl - v;
    if (t == 255) bsum[blockIdx.x] = incl;
}

__global__ __launch_bounds__(1024) void k_scan_top(int* __restrict__ bsum) {
    __shared__ int sh[1024];
    int t = threadIdx.x;
    int v = (t < SCAN_B) ? bsum[t] : 0;
    sh[t] = v;
    __syncthreads();
    #pragma unroll
    for (int off = 1; off < 1024; off <<= 1) {
        int x = (t >= off) ? sh[t - off] : 0;
        __syncthreads();
        sh[t] += x;
        __syncthreads();
    }
    if (t < SCAN_B) bsum[t] = sh[t] - v;   // exclusive
}

__global__ __launch_bounds__(256) void k_scan_add(int* __restrict__ rs,
                                                  const int* __restrict__ bsum) {
    int id = blockIdx.x * 256 + threadIdx.x;
    if (id < SCAN_N) rs[id] += bsum[id >> 8];
    if (id == 0) rs[SCAN_N] = TOTAL_SLOTS;
}

// ---------------- K4: CSR fill (pa edges, meta edges, self loops) ----------------
__global__ __launch_bounds__(256) void k_fill(const int* __restrict__ pa_src,
                                              const int* __restrict__ pa_dst,
                                              const int* __restrict__ ap_src,
                                              const int* __restrict__ meta_dst,
                                              const int* __restrict__ perm,
                                              const int* __restrict__ rs,
                                              int* __restrict__ cur2,
                                              int* __restrict__ col_src,
                                              int* __restrict__ col_ps) {   // col_ps indexed by (slot-EE)
    int id = blockIdx.x * 256 + threadIdx.x;
    if (id < EE) {                       // pa edge
        int d = pa_dst[id];
        int pos = atomicAdd(&cur2[d], 1);
        col_src[rs[d] + pos] = pa_src[id];
    } else if (id < 2 * EE) {            // meta edge
        int e = id - EE;
        int d = meta_dst[e];
        int pos = 1 + atomicAdd(&cur2[NN + d], 1);   // slot 0 reserved for self loop
        int idx = rs[NN + d] + pos;
        int s = ap_src[e];
        col_src[idx] = s;
        col_ps[idx - EE] = perm[s];
    } else if (id < 2 * EE + NN) {       // self loop
        int d = id - 2 * EE;
        int idx = rs[NN + d];
        col_src[idx] = d;
        col_ps[idx - EE] = perm[d];
    }
}

// ---------------- K5: SAGE mean-aggregate (gather, bf16 src, 4-way unrolled) ----------------
// one wave per dst row, lane = 2 dims
__global__ __launch_bounds__(256) void k_sage_gather(const int* __restrict__ rs,
                                                     const int* __restrict__ col_src,
                                                     const unsigned short* __restrict__ xbf,
                                                     unsigned short* __restrict__ mean_bf) {
    long gid = (long)blockIdx.x * 256 + threadIdx.x;
    int d = (int)(gid >> 6);
    if (d >= NN) return;
    int lane = (int)(gid & 63);
    int ks = rs[d], ke = rs[d + 1];
    float ax = 0.f, ay = 0.f;
    int i = ks;
    for (; i + 3 < ke; i += 4) {
        int s0 = col_src[i], s1 = col_src[i + 1], s2 = col_src[i + 2], s3 = col_src[i + 3];
        ushort2 v0 = ((const ushort2*)(xbf + (long)s0 * DD))[lane];
        ushort2 v1 = ((const ushort2*)(xbf + (long)s1 * DD))[lane];
        ushort2 v2 = ((const ushort2*)(xbf + (long)s2 * DD))[lane];
        ushort2 v3 = ((const ushort2*)(xbf + (long)s3 * DD))[lane];
        ax += (bf2f(v0.x) + bf2f(v1.x)) + (bf2f(v2.x) + bf2f(v3.x));
        ay += (bf2f(v0.y) + bf2f(v1.y)) + (bf2f(v2.y) + bf2f(v3.y));
    }
    for (; i < ke; ++i) {
        int s = col_src[i];
        ushort2 v = ((const ushort2*)(xbf + (long)s * DD))[lane];
        ax += bf2f(v.x);
        ay += bf2f(v.y);
    }
    float sc = 1.0f / fmaxf((float)(ke - ks), 1.0f);
    ushort2 w;
    w.x = f2bf(ax * sc);
    w.y = f2bf(ay * sc);
    ((ushort2*)(mean_bf + (long)d * DD))[lane] = w;
}

// ---------------- K6: h = lrelu(mean@Wl^T + x@Wr^T + b), store bf16 ----------------
__global__ __launch_bounds__(256) void k_sagegemm(const unsigned short* __restrict__ mean_bf,
                                                  const float* __restrict__ xa,
                                                  const float* __restrict__ Wl,
                                                  const float* __restrict__ Wr,
                                                  const float* __restrict__ sb,
                                                  unsigned short* __restrict__ h) {
    __shared__ unsigned short wlds[2][HH * DD];   // 64 KiB, bf16, XOR-swizzled
    int t = threadIdx.x;
    #pragma unroll
    for (int it = 0; it < 8; ++it) {
        int cid = t + it * 256;          // 2048 chunks of 8 elems
        int o = cid >> 4, c = cid & 15;
        int boff = (o * 256 + c * 16) ^ ((o & 7) << 4);
        {
            const float4* p = (const float4*)(Wl + (long)o * DD + c * 8);
            float4 a = p[0], b = p[1];
            short8v w;
            w[0]=(short)f2bf(a.x); w[1]=(short)f2bf(a.y); w[2]=(short)f2bf(a.z); w[3]=(short)f2bf(a.w);
            w[4]=(short)f2bf(b.x); w[5]=(short)f2bf(b.y); w[6]=(short)f2bf(b.z); w[7]=(short)f2bf(b.w);
            *(short8v*)((char*)(&wlds[0][0]) + boff) = w;
        }
        {
            const float4* p = (const float4*)(Wr + (long)o * DD + c * 8);
            float4 a = p[0], b = p[1];
            short8v w;
            w[0]=(short)f2bf(a.x); w[1]=(short)f2bf(a.y); w[2]=(short)f2bf(a.z); w[3]=(short)f2bf(a.w);
            w[4]=(short)f2bf(b.x); w[5]=(short)f2bf(b.y); w[6]=(short)f2bf(b.z); w[7]=(short)f2bf(b.w);
            *(short8v*)((char*)(&wlds[1][0]) + boff) = w;
        }
    }
    __syncthreads();

    int wave = t >> 6, lane = t & 63;
    int rowbase = blockIdx.x * 128 + wave * 32;
    int lr = lane & 15;
    int kq = (lane >> 4) * 8;
    int r0 = rowbase + lr, r1 = r0 + 16;
    int cr0 = (r0 < NN) ? r0 : 0;
    int cr1 = (r1 < NN) ? r1 : 0;

    f32x4 acc[2][8];
    #pragma unroll
    for (int i = 0; i < 2; ++i)
        #pragma unroll
        for (int j = 0; j < 8; ++j) { f32x4 z = {0.f,0.f,0.f,0.f}; acc[i][j] = z; }

    #pragma unroll
    for (int k0 = 0; k0 < DD; k0 += 32) {
        int kk = k0 + kq;
        short8v am0 = *(const short8v*)(mean_bf + (long)cr0 * DD + kk);
        short8v am1 = *(const short8v*)(mean_bf + (long)cr1 * DD + kk);
        const float4* q0 = (const float4*)(xa + (long)cr0 * DD + kk);
        const float4* q1 = (const float4*)(xa + (long)cr1 * DD + kk);
        float4 a0 = q0[0], b0 = q0[1], a1 = q1[0], b1 = q1[1];
        short8v ax0, ax1;
        ax0[0]=(short)f2bf(a0.x); ax0[1]=(short)f2bf(a0.y); ax0[2]=(short)f2bf(a0.z); ax0[3]=(short)f2bf(a0.w);
        ax0[4]=(short)f2bf(b0.x); ax0[5]=(short)f2bf(b0.y); ax0[6]=(short)f2bf(b0.z); ax0[7]=(short)f2bf(b0.w);
        ax1[0]=(short)f2bf(a1.x); ax1[1]=(short)f2bf(a1.y); ax1[2]=(short)f2bf(a1.z); ax1[3]=(short)f2bf(a1.w);
        ax1[4]=(short)f2bf(b1.x); ax1[5]=(short)f2bf(b1.y); ax1[6]=(short)f2bf(b1.z); ax1[7]=(short)f2bf(b1.w);
        #pragma unroll
        for (int nb = 0; nb < 8; ++nb) {
            int o = nb * 16 + lr;
            int boff = (o * 256 + kk * 2) ^ ((o & 7) << 4);
            short8v bl = *(const short8v*)((const char*)(&wlds[0][0]) + boff);
            short8v br = *(const short8v*)((const char*)(&wlds[1][0]) + boff);
            acc[0][nb] = __builtin_amdgcn_mfma_f32_16x16x32_bf16(am0, bl, acc[0][nb], 0, 0, 0);
            acc[1][nb] = __builtin_amdgcn_mfma_f32_16x16x32_bf16(am1, bl, acc[1][nb], 0, 0, 0);
            acc[0][nb] = __builtin_amdgcn_mfma_f32_16x16x32_bf16(ax0, br, acc[0][nb], 0, 0, 0);
            acc[1][nb] = __builtin_amdgcn_mfma_f32_16x16x32_bf16(ax1, br, acc[1][nb], 0, 0, 0);
        }
    }
    int q = lane >> 4;
    #pragma unroll
    for (int rh = 0; rh < 2; ++rh) {
        #pragma unroll
        for (int nb = 0; nb < 8; ++nb) {
            int col = nb * 16 + lr;
            float bias = sb[col];
            #pragma unroll
            for (int r = 0; r < 4; ++r) {
                int row = rowbase + rh * 16 + q * 4 + r;
                if (row < NN) {
                    float v = acc[rh][nb][r] + bias;
                    v = (v >= 0.f) ? v : 0.01f * v;
                    h[(long)row * HH + col] = f2bf(v);
                }
            }
        }
    }
}

// ---------------- K7: hg = h @ gatW^T, store bf16 ----------------
__global__ __launch_bounds__(256) void k_gatgemm(const unsigned short* __restrict__ h,
                                                 const float* __restrict__ Wg,
                                                 unsigned short* __restrict__ hg) {
    __shared__ unsigned short wlds[OO * HH];      // 16 KiB
    int t = threadIdx.x;
    #pragma unroll
    for (int it = 0; it < 4; ++it) {
        int cid = t + it * 256;          // 1024 chunks
        int o = cid >> 4, c = cid & 15;
        int boff = (o * 256 + c * 16) ^ ((o & 7) << 4);
        const float4* p = (const float4*)(Wg + (long)o * HH + c * 8);
        float4 a = p[0], b = p[1];
        short8v w;
        w[0]=(short)f2bf(a.x); w[1]=(short)f2bf(a.y); w[2]=(short)f2bf(a.z); w[3]=(short)f2bf(a.w);
        w[4]=(short)f2bf(b.x); w[5]=(short)f2bf(b.y); w[6]=(short)f2bf(b.z); w[7]=(short)f2bf(b.w);
        *(short8v*)((char*)(&wlds[0]) + boff) = w;
    }
    __syncthreads();

    int wave = t >> 6, lane = t & 63;
    int rowbase = blockIdx.x * 128 + wave * 32;
    int lr = lane & 15;
    int kq = (lane >> 4) * 8;
    int r0 = rowbase + lr, r1 = r0 + 16;
    int cr0 = (r0 < NN) ? r0 : 0;
    int cr1 = (r1 < NN) ? r1 : 0;

    f32x4 acc[2][4];
    #pragma unroll
    for (int i = 0; i < 2; ++i)
        #pragma unroll
        for (int j = 0; j < 4; ++j) { f32x4 z = {0.f,0.f,0.f,0.f}; acc[i][j] = z; }

    #pragma unroll
    for (int k0 = 0; k0 < HH; k0 += 32) {
        int kk = k0 + kq;
        short8v a0 = *(const short8v*)(h + (long)cr0 * HH + kk);
        short8v a1 = *(const short8v*)(h + (long)cr1 * HH + kk);
        #pragma unroll
        for (int nb = 0; nb < 4; ++nb) {
            int o = nb * 16 + lr;
            int boff = (o * 256 + kk * 2) ^ ((o & 7) << 4);
            short8v b = *(const short8v*)((const char*)(&wlds[0]) + boff);
            acc[0][nb] = __builtin_amdgcn_mfma_f32_16x16x32_bf16(a0, b, acc[0][nb], 0, 0, 0);
            acc[1][nb] = __builtin_amdgcn_mfma_f32_16x16x32_bf16(a1, b, acc[1][nb], 0, 0, 0);
        }
    }
    int q = lane >> 4;
    #pragma unroll
    for (int rh = 0; rh < 2; ++rh)
        #pragma unroll
        for (int nb = 0; nb < 4; ++nb)
            #pragma unroll
            for (int r = 0; r < 4; ++r) {
                int row = rowbase + rh * 16 + q * 4 + r;
                if (row < NN) hg[(long)row * OO + nb * 16 + lr] = f2bf(acc[rh][nb][r]);
            }
}

// ---------------- K8: alpha_src/alpha_dst dots (wave per row, shfl reduce) ----------------
__global__ __launch_bounds__(256) void k_alpha(const unsigned short* __restrict__ hg,
                                               const float* __restrict__ asrc,
                                               const float* __restrict__ adst,
                                               float* __restrict__ al_s,
                                               float* __restrict__ al_d) {
    long gid = (long)blockIdx.x * 256 + threadIdx.x;
    int row = (int)(gid >> 6);
    if (row >= NN) return;
    int j = (int)(gid & 63);
    float v = bf2f(hg[(long)row * OO + j]);
    float s = v * asrc[j];
    float d = v * adst[j];
    #pragma unroll
    for (int off = 32; off; off >>= 1) {
        s += __shfl_xor(s, off, 64);
        d += __shfl_xor(d, off, 64);
    }
    if (j == 0) { al_s[row] = s; al_d[row] = d; }
}

// ---------------- K9: GAT one-pass softmax-aggregate (gather), bias+PReLU fused ----------------
// one wave per dst row, lane = output dim, inline exp from L2-resident al arrays
__global__ __launch_bounds__(256) void k_gat_gather(const int* __restrict__ rs,
                                                    const int* __restrict__ col_src,
                                                    const int* __restrict__ col_ps,   // indexed by slot-EE
                                                    const int* __restrict__ perm,
                                                    const float* __restrict__ al_s,
                                                    const float* __restrict__ al_d,
                                                    const unsigned short* __restrict__ hg,
                                                    const float* __restrict__ gb,
                                                    const float* __restrict__ prelu_a,
                                                    float* __restrict__ out_pos,
                                                    float* __restrict__ out_neg) {
    long gid = (long)blockIdx.x * 256 + threadIdx.x;
    int d = (int)(gid >> 6);
    if (d >= NN) return;
    int j = (int)(gid & 63);
    int ks = rs[NN + d], ke = rs[NN + d + 1];
    float add = al_d[d];
    float adn = al_d[perm[d]];
    float accp = 0.f, denp = 0.f, accn = 0.f, denn = 0.f;
    int i = ks;
    for (; i + 3 < ke; i += 4) {
        int s0 = col_src[i], s1 = col_src[i + 1], s2 = col_src[i + 2], s3 = col_src[i + 3];
        int q0 = col_ps[i - EE], q1 = col_ps[i + 1 - EE], q2 = col_ps[i + 2 - EE], q3 = col_ps[i + 3 - EE];
        float h0 = bf2f(hg[(long)s0 * OO + j]);
        float h1 = bf2f(hg[(long)s1 * OO + j]);
        float h2 = bf2f(hg[(long)s2 * OO + j]);
        float h3 = bf2f(hg[(long)s3 * OO + j]);
        float g0 = bf2f(hg[(long)q0 * OO + j]);
        float g1 = bf2f(hg[(long)q1 * OO + j]);
        float g2 = bf2f(hg[(long)q2 * OO + j]);
        float g3 = bf2f(hg[(long)q3 * OO + j]);
        float l0 = al_s[s0] + add, l1 = al_s[s1] + add, l2 = al_s[s2] + add, l3 = al_s[s3] + add;
        l0 = (l0 >= 0.f) ? l0 : 0.2f * l0;  l1 = (l1 >= 0.f) ? l1 : 0.2f * l1;
        l2 = (l2 >= 0.f) ? l2 : 0.2f * l2;  l3 = (l3 >= 0.f) ? l3 : 0.2f * l3;
        float x0 = __expf(l0), x1 = __expf(l1), x2 = __expf(l2), x3 = __expf(l3);
        float m0 = al_s[q0] + adn, m1 = al_s[q1] + adn, m2 = al_s[q2] + adn, m3 = al_s[q3] + adn;
        m0 = (m0 >= 0.f) ? m0 : 0.2f * m0;  m1 = (m1 >= 0.f) ? m1 : 0.2f * m1;
        m2 = (m2 >= 0.f) ? m2 : 0.2f * m2;  m3 = (m3 >= 0.f) ? m3 : 0.2f * m3;
        float y0 = __expf(m0), y1 = __expf(m1), y2 = __expf(m2), y3 = __expf(m3);
        denp += (x0 + x1) + (x2 + x3);
        denn += (y0 + y1) + (y2 + y3);
        accp += (x0 * h0 + x1 * h1) + (x2 * h2 + x3 * h3);
        accn += (y0 * g0 + y1 * g1) + (y2 * g2 + y3 * g3);
    }
    for (; i < ke; ++i) {
        int s = col_src[i];
        int q = col_ps[i - EE];
        float h = bf2f(hg[(long)s * OO + j]);
        float g = bf2f(hg[(long)q * OO + j]);
        float l = al_s[s] + add;
        l = (l >= 0.f) ? l : 0.2f * l;
        float x = __expf(l);
        float m = al_s[q] + adn;
        m = (m >= 0.f) ? m : 0.2f * m;
        float y = __expf(m);
        denp += x; denn += y;
        accp += x * h; accn += y * g;
    }
    float bias = gb[j];
    float a = prelu_a[0];
    float vp = accp / denp + bias;
    vp = (vp >= 0.f) ? vp : a * vp;
    out_pos[(long)d * OO + j] = vp;
    float vn = accn / denn + bias;
    vn = (vn >= 0.f) ? vn : a * vn;
    out_neg[(long)d * OO + j] = vn;
}

// ---------------- K10: summary mean over pos rows ----------------
__global__ __launch_bounds__(256) void k_summary(const float* __restrict__ out_pos,
                                                 float* __restrict__ summary) {
    int t = threadIdx.x;
    int j = t & 63, sub = t >> 6;
    float acc = 0.f;
    for (int row = blockIdx.x * 4 + sub; row < NN; row += 256 * 4) {
        acc += out_pos[(long)row * OO + j];
    }
    __shared__ float red[4][OO];
    red[sub][j] = acc;
    __syncthreads();
    if (sub == 0) {
        float ttl = red[0][j] + red[1][j] + red[2][j] + red[3][j];
        atomicAdd(summary + j, ttl * (1.0f / NN));
    }
}

extern "C" void kernel_launch(void* const* d_in, const int* in_sizes, int n_in,
                              void* d_out, int out_size, void* d_ws, size_t ws_size,
                              hipStream_t stream) {
    const float* x_author = (const float*)d_in[0];
    const float* x_paper  = (const float*)d_in[1];
    const float* sage_Wl  = (const float*)d_in[2];
    const float* sage_Wr  = (const float*)d_in[3];
    const float* sage_b   = (const float*)d_in[4];
    const float* gat_W    = (const float*)d_in[5];
    const float* gat_as   = (const float*)d_in[6];
    const float* gat_ad   = (const float*)d_in[7];
    const float* gat_b    = (const float*)d_in[8];
    const float* prelu_a  = (const float*)d_in[9];
    const int*   edge_ap  = (const int*)d_in[10];
    const int*   edge_pa  = (const int*)d_in[11];
    const int*   perm     = (const int*)d_in[12];

    char* ws = (char*)d_ws;
    unsigned long long* p2a = (unsigned long long*)(ws + 0);       //   800,000
    int*   cnt2      = (int*)(ws + 800000);                        //   800,000
    int*   cur2      = (int*)(ws + 1600000);                       //   800,000
    // --- zeroed region ends at 2,400,000 ---
    int*   rs        = (int*)(ws + 2400000);                       //   800,016 (200001 ints)
    int*   bsum      = (int*)(ws + 3200016);                       //     4,096
    int*   meta      = (int*)(ws + 3204112);                       // 3,200,000
    int*   col_src   = (int*)(ws + 6404112);                       // 6,800,000 (1.7M slots)
    int*   col_ps    = (int*)(ws + 13204112);                      // 3,600,000 (meta slots only)
    float* al_s      = (float*)(ws + 16804112);                    //   400,000
    float* al_d      = (float*)(ws + 17204112);                    //   400,000
    unsigned short* xbf     = (unsigned short*)(ws + 17604112);    // 25,600,000 (reused as h)
    unsigned short* mean_bf = (unsigned short*)(ws + 43204112);    // 25,600,000
    unsigned short* hg      = (unsigned short*)(ws + 68804112);    // 12,800,000
    // total = 81,604,112 bytes
    unsigned short* h = xbf;   // xbf dead after k_sage_gather; stream-ordered reuse

    hipMemsetAsync(d_ws, 0, 2400000, stream);
    hipMemsetAsync((char*)d_out + (size_t)2 * NN * OO * sizeof(float), 0,
                   OO * sizeof(float), stream);

    const float* Wl = sage_Wl + 3 * HH * DD;   // [l=1][et=1]
    const float* Wr = sage_Wr + 3 * HH * DD;
    const float* sb = sage_b  + 3 * HH;

    k_cast<<<(NN * DD / 4 + 255) / 256, 256, 0, stream>>>(x_paper, xbf);
    k_p2a<<<(EE + 255) / 256, 256, 0, stream>>>(edge_pa, edge_pa + EE, p2a, cnt2);
    k_meta<<<(EE + NN + 255) / 256, 256, 0, stream>>>(edge_ap + EE, p2a, meta, cnt2);
    k_scan_block<<<SCAN_B, 256, 0, stream>>>(cnt2, rs, bsum);
    k_scan_top<<<1, 1024, 0, stream>>>(bsum);
    k_scan_add<<<SCAN_B, 256, 0, stream>>>(rs, bsum);
    k_fill<<<(2 * EE + NN + 255) / 256, 256, 0, stream>>>(edge_pa, edge_pa + EE,
                                                          edge_ap, meta, perm, rs, cur2,
                                                          col_src, col_ps);
    k_sage_gather<<<(NN * 64 + 255) / 256, 256, 0, stream>>>(rs, col_src, xbf, mean_bf);
    k_sagegemm<<<(NN + 127) / 128, 256, 0, stream>>>(mean_bf, x_author, Wl, Wr, sb, h);
    k_gatgemm<<<(NN + 127) / 128, 256, 0, stream>>>(h, gat_W, hg);
    k_alpha<<<(NN * 64 + 255) / 256, 256, 0, stream>>>(hg, gat_as, gat_ad, al_s, al_d);
    k_gat_gather<<<(NN * 64 + 255) / 256, 256, 0, stream>>>(rs, col_src, col_ps, perm,
                                                            al_s, al_d, hg, gat_b, prelu_a,
                                                            (float*)d_out,
                                                            (float*)d_out + (long)NN * OO);
    k_summary<<<256, 256, 0, stream>>>((float*)d_out, (float*)d_out + 2L * NN * OO);
}